// Round 10
// baseline (393.081 us; speedup 1.0000x reference)
//
#include <hip/hip_runtime.h>
#include <math.h>

#define NN 4096
#define SS 64
#define DD 64
#define HH 256
#define FF 256
// chunk_size fixed at 256 by setup_inputs(); 16 chunks of 256.

__device__ __forceinline__ float waveReduce(float v) {
#pragma unroll
  for (int o = 32; o > 0; o >>= 1) v += __shfl_down(v, o, 64);
  return v;
}
__device__ __forceinline__ float waveReduceXor(float v) {
#pragma unroll
  for (int o = 32; o > 0; o >>= 1) v += __shfl_xor(v, o, 64);
  return v;
}

// acc: 0=c_num 1=f_num 2=b_num 3=msum 4=sig_sum 5=loss1 6=loss2 7=loss4 8=block_count
__global__ void k_zero(double* __restrict__ acc) {
  if (threadIdx.x < 16) acc[threadIdx.x] = 0.0;
}

__global__ void k_scalar(const float* __restrict__ rgbs, const float* __restrict__ ray_mask,
                         const float* __restrict__ coarse, const float* __restrict__ fine,
                         const float* __restrict__ beta, const float* __restrict__ sig,
                         double* __restrict__ acc) {
  int tid = blockIdx.x * blockDim.x + threadIdx.x;  // 4096 threads
  float c = 0.f, f = 0.f, b = 0.f, m = 0.f, s = 0.f;
  if (tid < NN) {
    float mk = ray_mask[tid];
    float bt = beta[tid];
    float inv2b2 = 1.0f / (2.0f * bt * bt);
#pragma unroll
    for (int ch = 0; ch < 3; ++ch) {
      float r = rgbs[tid * 3 + ch];
      float dc = coarse[tid * 3 + ch] - r;
      float df = fine[tid * 3 + ch] - r;
      c += dc * dc * mk;
      f += df * df * inv2b2 * mk;
    }
    c *= 0.5f;
    b = logf(bt) * mk;
    m = mk;
  }
  for (int i = tid; i < NN * SS; i += NN) s += sig[i];
  c = waveReduce(c); f = waveReduce(f); b = waveReduce(b); m = waveReduce(m); s = waveReduce(s);
  if ((threadIdx.x & 63) == 0) {
    atomicAdd(&acc[0], (double)c);
    atomicAdd(&acc[1], (double)f);
    atomicAdd(&acc[2], (double)b);
    atomicAdd(&acc[3], (double)m);
    atomicAdd(&acc[4], (double)s);
  }
}

// feat[n][d] = sum_s pt[n][s][d] * w[n][s].  One wave per n, float4 loads.
__global__ void k_feat(const float* __restrict__ pt, const float* __restrict__ w,
                       float* __restrict__ feat) {
  int wave = (blockIdx.x * blockDim.x + threadIdx.x) >> 6;
  int lane = threadIdx.x & 63;
  if (wave >= NN) return;
  const float4* p4 = (const float4*)(pt + (size_t)wave * SS * DD);
  const float* wr = w + wave * SS;
  float a0 = 0.f, a1 = 0.f, a2 = 0.f, a3 = 0.f;
#pragma unroll
  for (int it = 0; it < 16; ++it) {
    float4 v = p4[it * 64 + lane];
    float ws = wr[it * 4 + (lane >> 4)];
    a0 += v.x * ws; a1 += v.y * ws; a2 += v.z * ws; a3 += v.w * ws;
  }
  a0 += __shfl_xor(a0, 16, 64); a1 += __shfl_xor(a1, 16, 64);
  a2 += __shfl_xor(a2, 16, 64); a3 += __shfl_xor(a3, 16, 64);
  a0 += __shfl_xor(a0, 32, 64); a1 += __shfl_xor(a1, 32, 64);
  a2 += __shfl_xor(a2, 32, 64); a3 += __shfl_xor(a3, 32, 64);
  if (lane < 16) {
    float4 o = make_float4(a0, a1, a2, a3);
    ((float4*)(feat + wave * DD))[lane] = o;
  }
}

// h[n][j] = relu(feat[n][:] @ W1[0:64][j] + scale_n*W1[64][j])
// block: 16 n-rows; wave w -> 4 rows; lane -> 4 j (wave covers all 256 j).
__global__ void k_h(const float* __restrict__ feat, const float* __restrict__ scales,
                    const float* __restrict__ W1, float* __restrict__ h, int larger) {
  int w = threadIdx.x >> 6, lane = threadIdx.x & 63;
  int j0 = 4 * lane;
  int nb = blockIdx.x * 16 + w * 4;
  float a[4][4];
#pragma unroll
  for (int r = 0; r < 4; ++r)
#pragma unroll
    for (int jj = 0; jj < 4; ++jj) a[r][jj] = 0.f;
#pragma unroll 8
  for (int k = 0; k < DD; ++k) {
    float4 wv = *(const float4*)&W1[k * HH + j0];
#pragma unroll
    for (int r = 0; r < 4; ++r) {
      float fv = feat[(nb + r) * DD + k];  // wave-uniform -> s_load
      a[r][0] += fv * wv.x; a[r][1] += fv * wv.y;
      a[r][2] += fv * wv.z; a[r][3] += fv * wv.w;
    }
  }
  float4 wl = *(const float4*)&W1[DD * HH + j0];
#pragma unroll
  for (int r = 0; r < 4; ++r) {
    float sc = scales[nb + r];
    if (larger) sc = sc + fmaxf(0.f, 2.0f - sc) * 0.5f;
    float4 o;
    o.x = fmaxf(a[r][0] + sc * wl.x, 0.f);
    o.y = fmaxf(a[r][1] + sc * wl.y, 0.f);
    o.z = fmaxf(a[r][2] + sc * wl.z, 0.f);
    o.w = fmaxf(a[r][3] + sc * wl.w, 0.f);
    *(float4*)&h[(nb + r) * HH + j0] = o;
  }
}

// g = normalize(h @ W2). Block: 8 n-rows; waves split k (4 x 64); lane -> 4 j.
// Cross-wave reduce via padded LDS; LDS transpose for coalesced gT writes.
__global__ void k_g(const float* __restrict__ h, const float* __restrict__ W2,
                    float* __restrict__ g, float* __restrict__ gT, float* __restrict__ sqn) {
  int n0 = blockIdx.x * 8;
  int w = threadIdx.x >> 6, lane = threadIdx.x & 63;
  int j0 = 4 * lane;
  int kb = w * 64;
  float a[8][4];
#pragma unroll
  for (int r = 0; r < 8; ++r)
#pragma unroll
    for (int jj = 0; jj < 4; ++jj) a[r][jj] = 0.f;
#pragma unroll 8
  for (int kk = 0; kk < 64; kk += 4) {
    int k = kb + kk;
    float4 w0 = *(const float4*)&W2[(k + 0) * FF + j0];
    float4 w1 = *(const float4*)&W2[(k + 1) * FF + j0];
    float4 w2 = *(const float4*)&W2[(k + 2) * FF + j0];
    float4 w3 = *(const float4*)&W2[(k + 3) * FF + j0];
#pragma unroll
    for (int r = 0; r < 8; ++r) {
      float4 hv = *(const float4*)&h[(n0 + r) * HH + k];  // wave-uniform
      a[r][0] += hv.x * w0.x + hv.y * w1.x + hv.z * w2.x + hv.w * w3.x;
      a[r][1] += hv.x * w0.y + hv.y * w1.y + hv.z * w2.y + hv.w * w3.y;
      a[r][2] += hv.x * w0.z + hv.y * w1.z + hv.z * w2.z + hv.w * w3.z;
      a[r][3] += hv.x * w0.w + hv.y * w1.w + hv.z * w2.w + hv.w * w3.w;
    }
  }
  __shared__ float red[4][64][33];
  __shared__ float trans[8][FF];
#pragma unroll
  for (int r = 0; r < 8; ++r)
#pragma unroll
    for (int jj = 0; jj < 4; ++jj) red[w][lane][4 * r + jj] = a[r][jj];
  __syncthreads();
  // thread (w,lane) owns rows 2w, 2w+1 at its 4 j's
#pragma unroll
  for (int rr = 0; rr < 2; ++rr) {
    int r = 2 * w + rr;
    float d0 = red[0][lane][4 * r + 0] + red[1][lane][4 * r + 0] + red[2][lane][4 * r + 0] + red[3][lane][4 * r + 0];
    float d1 = red[0][lane][4 * r + 1] + red[1][lane][4 * r + 1] + red[2][lane][4 * r + 1] + red[3][lane][4 * r + 1];
    float d2 = red[0][lane][4 * r + 2] + red[1][lane][4 * r + 2] + red[2][lane][4 * r + 2] + red[3][lane][4 * r + 2];
    float d3 = red[0][lane][4 * r + 3] + red[1][lane][4 * r + 3] + red[2][lane][4 * r + 3] + red[3][lane][4 * r + 3];
    float ss = waveReduceXor(d0 * d0 + d1 * d1 + d2 * d2 + d3 * d3);
    float inv = 1.0f / (sqrtf(ss) + 1e-6f);
    float4 v = make_float4(d0 * inv, d1 * inv, d2 * inv, d3 * inv);
    *(float4*)&g[(size_t)(n0 + r) * FF + j0] = v;
    if (lane == 0) sqn[n0 + r] = ss * inv * inv;
    ((float4*)&trans[r][0])[lane] = v;
  }
  __syncthreads();
  // coalesced-ish gT write: thread tj owns column j=tj, rows n0..n0+7
  int tj = threadIdx.x;
  float4 lo = make_float4(trans[0][tj], trans[1][tj], trans[2][tj], trans[3][tj]);
  float4 hi = make_float4(trans[4][tj], trans[5][tj], trans[6][tj], trans[7][tj]);
  *(float4*)(gT + (size_t)tj * NN + n0) = lo;
  *(float4*)(gT + (size_t)tj * NN + n0 + 4) = hi;
}

// Pairwise masked loss. Block: (chunk c, i-group of 8). Wave = 64-j tile,
// lane quads split k (4 x 64), shfl_xor reduce; lane quad 0 does epilogue.
__global__ void k_pair(const float* __restrict__ g, const float* __restrict__ gT,
                       const float* __restrict__ sqn, const int* __restrict__ labels,
                       const float* __restrict__ beta, double* __restrict__ acc, int pass) {
  int c = blockIdx.x >> 5, ig = blockIdx.x & 31;
  int i0 = c * 256 + ig * 8;
  int wv = threadIdx.x >> 6;          // j-tile
  int lane = threadIdx.x & 63;
  int ksub = lane >> 4;               // 0..3 -> k segment
  int jl0 = wv * 64 + (lane & 15) * 4;  // chunk-local j base
  float fl1 = 0.f, fl4 = 0.f, fcnt = 0.f;
  if (wv * 64 + 63 >= ig * 8) {       // triangle tile skip (wave-uniform)
    float a[8][4];
#pragma unroll
    for (int r = 0; r < 8; ++r)
#pragma unroll
      for (int jj = 0; jj < 4; ++jj) a[r][jj] = 0.f;
    int kb = ksub * 64;
    const float* gtb = gT + (size_t)c * 256 + jl0;
#pragma unroll 8
    for (int kk = 0; kk < 64; kk += 4) {
      int k = kb + kk;
      float4 b0 = *(const float4*)(gtb + (size_t)(k + 0) * NN);
      float4 b1 = *(const float4*)(gtb + (size_t)(k + 1) * NN);
      float4 b2 = *(const float4*)(gtb + (size_t)(k + 2) * NN);
      float4 b3 = *(const float4*)(gtb + (size_t)(k + 3) * NN);
#pragma unroll
      for (int r = 0; r < 8; ++r) {
        float4 gi = *(const float4*)(g + (size_t)(i0 + r) * FF + k);
        a[r][0] += gi.x * b0.x + gi.y * b1.x + gi.z * b2.x + gi.w * b3.x;
        a[r][1] += gi.x * b0.y + gi.y * b1.y + gi.z * b2.y + gi.w * b3.y;
        a[r][2] += gi.x * b0.z + gi.y * b1.z + gi.z * b2.z + gi.w * b3.z;
        a[r][3] += gi.x * b0.w + gi.y * b1.w + gi.z * b2.w + gi.w * b3.w;
      }
    }
    // reduce over the 4 k-segments: lanes l, l^16, l^32
#pragma unroll
    for (int r = 0; r < 8; ++r)
#pragma unroll
      for (int jj = 0; jj < 4; ++jj) {
        float v = a[r][jj];
        v += __shfl_xor(v, 16, 64);
        v += __shfl_xor(v, 32, 64);
        a[r][jj] = v;
      }
    if (ksub == 0) {
#pragma unroll
      for (int r = 0; r < 8; ++r) {
        int i = i0 + r, il = ig * 8 + r;
        int li = labels[i];
        float sqi = sqn[i];
        bool sti = beta[i] < 0.15f;
#pragma unroll
        for (int jj = 0; jj < 4; ++jj) {
          int jl = jl0 + jj;
          if (jl >= il) {
            int jg = c * 256 + jl;
            int lj = labels[jg];
            if (li != -1 && lj != -1) {
              fcnt += 1.0f;
              if (sti || beta[jg] < 0.15f) {
                float d2 = sqi + sqn[jg] - 2.0f * a[r][jj];
                float d = sqrtf(fmaxf(d2, 1e-12f));
                if (li == lj) {
                  if (jl != il) fl1 += d;
                } else {
                  fl4 += fmaxf(0.f, 1.0f - d);
                }
              }
            }
          }
        }
      }
    }
  }
  fl1 = waveReduce(fl1);
  fl4 = waveReduce(fl4);
  fcnt = waveReduce(fcnt);
  if (lane == 0) {
    if (pass == 0) {
      if (fl1 != 0.f) atomicAdd(&acc[5], (double)fl1);
      if (fl4 != 0.f) atomicAdd(&acc[7], (double)fl4);
      if (fcnt != 0.f) atomicAdd(&acc[8], (double)fcnt);
    } else {
      if (fl1 != 0.f) atomicAdd(&acc[6], (double)fl1);
    }
  }
}

__global__ void k_final(const double* __restrict__ acc, float* __restrict__ out) {
  if (threadIdx.x == 0) {
    double msum = acc[3] + 1e-20;
    out[0] = (float)(acc[0] / msum);
    out[1] = (float)(acc[1] / msum);
    out[2] = (float)(3.0 + acc[2] / msum);
    out[3] = (float)(0.01 * acc[4] / (double)(NN * SS));
    out[4] = (float)((acc[5] + acc[6] + acc[7]) / acc[8]);
  }
}

extern "C" void kernel_launch(void* const* d_in, const int* in_sizes, int n_in,
                              void* d_out, int out_size, void* d_ws, size_t ws_size,
                              hipStream_t stream) {
  const float* rgbs      = (const float*)d_in[0];
  const float* ray_mask  = (const float*)d_in[1];
  const float* rgb_coarse= (const float*)d_in[2];
  const float* rgb_fine  = (const float*)d_in[3];
  const float* beta      = (const float*)d_in[4];
  const float* sig       = (const float*)d_in[5];
  const float* pt        = (const float*)d_in[6];
  const float* wfs       = (const float*)d_in[7];
  const float* scales    = (const float*)d_in[8];
  const float* W1        = (const float*)d_in[9];
  const float* W2        = (const float*)d_in[10];
  const int*   labels    = (const int*)d_in[11];
  float* out = (float*)d_out;

  char* w = (char*)d_ws;
  double* acc = (double*)w;            // 16 doubles
  float* feat = (float*)(w + 256);     // N*64
  float* h    = feat + NN * DD;        // N*256
  float* g    = h + NN * HH;           // N*256
  float* gT   = g + NN * FF;           // N*256
  float* sqn  = gT + NN * FF;          // N

  k_zero<<<1, 64, 0, stream>>>(acc);
  k_scalar<<<16, 256, 0, stream>>>(rgbs, ray_mask, rgb_coarse, rgb_fine, beta, sig, acc);
  k_feat<<<1024, 256, 0, stream>>>(pt, wfs, feat);

  // pass 0: original scales -> loss1, loss4, block count
  k_h<<<256, 256, 0, stream>>>(feat, scales, W1, h, 0);
  k_g<<<512, 256, 0, stream>>>(h, W2, g, gT, sqn);
  k_pair<<<512, 256, 0, stream>>>(g, gT, sqn, labels, beta, acc, 0);

  // pass 1: larger scales -> loss2
  k_h<<<256, 256, 0, stream>>>(feat, scales, W1, h, 1);
  k_g<<<512, 256, 0, stream>>>(h, W2, g, gT, sqn);
  k_pair<<<512, 256, 0, stream>>>(g, gT, sqn, labels, beta, acc, 1);

  k_final<<<1, 64, 0, stream>>>(acc, out);
}

// Round 11
// 364.182 us; speedup vs baseline: 1.0794x; 1.0794x over previous
//
#include <hip/hip_runtime.h>
#include <math.h>

#define NN 4096
#define SS 64
#define DD 64
#define HH 256
#define FF 256
// chunk_size fixed at 256 by setup_inputs(); 16 chunks of 256.

__device__ __forceinline__ float waveReduce(float v) {
#pragma unroll
  for (int o = 32; o > 0; o >>= 1) v += __shfl_down(v, o, 64);
  return v;
}
__device__ __forceinline__ float waveReduceXor(float v) {
#pragma unroll
  for (int o = 32; o > 0; o >>= 1) v += __shfl_xor(v, o, 64);
  return v;
}

// acc: 0=c_num 1=f_num 2=b_num 3=msum 4=sig_sum 5=loss1 6=loss2 7=loss4 8=block_count
__global__ void k_zero(double* __restrict__ acc) {
  if (threadIdx.x < 16) acc[threadIdx.x] = 0.0;
}

__global__ void k_scalar(const float* __restrict__ rgbs, const float* __restrict__ ray_mask,
                         const float* __restrict__ coarse, const float* __restrict__ fine,
                         const float* __restrict__ beta, const float* __restrict__ sig,
                         double* __restrict__ acc) {
  int tid = blockIdx.x * blockDim.x + threadIdx.x;  // 4096 threads
  float c = 0.f, f = 0.f, b = 0.f, m = 0.f, s = 0.f;
  if (tid < NN) {
    float mk = ray_mask[tid];
    float bt = beta[tid];
    float inv2b2 = 1.0f / (2.0f * bt * bt);
#pragma unroll
    for (int ch = 0; ch < 3; ++ch) {
      float r = rgbs[tid * 3 + ch];
      float dc = coarse[tid * 3 + ch] - r;
      float df = fine[tid * 3 + ch] - r;
      c += dc * dc * mk;
      f += df * df * inv2b2 * mk;
    }
    c *= 0.5f;
    b = logf(bt) * mk;
    m = mk;
  }
  for (int i = tid; i < NN * SS; i += NN) s += sig[i];
  c = waveReduce(c); f = waveReduce(f); b = waveReduce(b); m = waveReduce(m); s = waveReduce(s);
  if ((threadIdx.x & 63) == 0) {
    atomicAdd(&acc[0], (double)c);
    atomicAdd(&acc[1], (double)f);
    atomicAdd(&acc[2], (double)b);
    atomicAdd(&acc[3], (double)m);
    atomicAdd(&acc[4], (double)s);
  }
}

// feat[n][d] = sum_s pt[n][s][d] * w[n][s].  One wave per n, float4 loads.
__global__ void k_feat(const float* __restrict__ pt, const float* __restrict__ w,
                       float* __restrict__ feat) {
  int wave = (blockIdx.x * blockDim.x + threadIdx.x) >> 6;
  int lane = threadIdx.x & 63;
  if (wave >= NN) return;
  const float4* p4 = (const float4*)(pt + (size_t)wave * SS * DD);
  const float* wr = w + wave * SS;
  float a0 = 0.f, a1 = 0.f, a2 = 0.f, a3 = 0.f;
#pragma unroll
  for (int it = 0; it < 16; ++it) {
    float4 v = p4[it * 64 + lane];
    float ws = wr[it * 4 + (lane >> 4)];
    a0 += v.x * ws; a1 += v.y * ws; a2 += v.z * ws; a3 += v.w * ws;
  }
  a0 += __shfl_xor(a0, 16, 64); a1 += __shfl_xor(a1, 16, 64);
  a2 += __shfl_xor(a2, 16, 64); a3 += __shfl_xor(a3, 16, 64);
  a0 += __shfl_xor(a0, 32, 64); a1 += __shfl_xor(a1, 32, 64);
  a2 += __shfl_xor(a2, 32, 64); a3 += __shfl_xor(a3, 32, 64);
  if (lane < 16) {
    float4 o = make_float4(a0, a1, a2, a3);
    ((float4*)(feat + wave * DD))[lane] = o;
  }
}

// h[n][j] = relu(feat[n][:] @ W1[0:64][j] + scale_n*W1[64][j])
// block: 16 n-rows; wave w -> 4 rows; lane -> 4 j (wave covers all 256 j).
// launch_bounds(256,4): cap 128 VGPR, no spill (need ~40).
__global__ void __launch_bounds__(256, 4)
k_h(const float* __restrict__ feat, const float* __restrict__ scales,
    const float* __restrict__ W1, float* __restrict__ h, int larger) {
  int w = threadIdx.x >> 6, lane = threadIdx.x & 63;
  int j0 = 4 * lane;
  int nb = blockIdx.x * 16 + w * 4;
  float a[4][4];
#pragma unroll
  for (int r = 0; r < 4; ++r)
#pragma unroll
    for (int jj = 0; jj < 4; ++jj) a[r][jj] = 0.f;
#pragma unroll 8
  for (int k = 0; k < DD; ++k) {
    float4 wv = *(const float4*)&W1[k * HH + j0];
#pragma unroll
    for (int r = 0; r < 4; ++r) {
      float fv = feat[(nb + r) * DD + k];  // wave-uniform -> s_load
      a[r][0] += fv * wv.x; a[r][1] += fv * wv.y;
      a[r][2] += fv * wv.z; a[r][3] += fv * wv.w;
    }
  }
  float4 wl = *(const float4*)&W1[DD * HH + j0];
#pragma unroll
  for (int r = 0; r < 4; ++r) {
    float sc = scales[nb + r];
    if (larger) sc = sc + fmaxf(0.f, 2.0f - sc) * 0.5f;
    float4 o;
    o.x = fmaxf(a[r][0] + sc * wl.x, 0.f);
    o.y = fmaxf(a[r][1] + sc * wl.y, 0.f);
    o.z = fmaxf(a[r][2] + sc * wl.z, 0.f);
    o.w = fmaxf(a[r][3] + sc * wl.w, 0.f);
    *(float4*)&h[(nb + r) * HH + j0] = o;
  }
}

// g = normalize(h @ W2). Block: 8 n-rows; waves split k (4 x 64); lane -> 4 j.
// launch_bounds(256,4): cap 128 VGPR — kills the 64-VGPR spill seen in r10.
__global__ void __launch_bounds__(256, 4)
k_g(const float* __restrict__ h, const float* __restrict__ W2,
    float* __restrict__ g, float* __restrict__ gT, float* __restrict__ sqn) {
  int n0 = blockIdx.x * 8;
  int w = threadIdx.x >> 6, lane = threadIdx.x & 63;
  int j0 = 4 * lane;
  int kb = w * 64;
  float a[8][4];
#pragma unroll
  for (int r = 0; r < 8; ++r)
#pragma unroll
    for (int jj = 0; jj < 4; ++jj) a[r][jj] = 0.f;
#pragma unroll 8
  for (int kk = 0; kk < 64; kk += 4) {
    int k = kb + kk;
    float4 w0 = *(const float4*)&W2[(k + 0) * FF + j0];
    float4 w1 = *(const float4*)&W2[(k + 1) * FF + j0];
    float4 w2 = *(const float4*)&W2[(k + 2) * FF + j0];
    float4 w3 = *(const float4*)&W2[(k + 3) * FF + j0];
#pragma unroll
    for (int r = 0; r < 8; ++r) {
      float4 hv = *(const float4*)&h[(n0 + r) * HH + k];  // wave-uniform
      a[r][0] += hv.x * w0.x + hv.y * w1.x + hv.z * w2.x + hv.w * w3.x;
      a[r][1] += hv.x * w0.y + hv.y * w1.y + hv.z * w2.y + hv.w * w3.y;
      a[r][2] += hv.x * w0.z + hv.y * w1.z + hv.z * w2.z + hv.w * w3.z;
      a[r][3] += hv.x * w0.w + hv.y * w1.w + hv.z * w2.w + hv.w * w3.w;
    }
  }
  __shared__ float red[4][64][33];
  __shared__ float trans[8][FF];
#pragma unroll
  for (int r = 0; r < 8; ++r)
#pragma unroll
    for (int jj = 0; jj < 4; ++jj) red[w][lane][4 * r + jj] = a[r][jj];
  __syncthreads();
  // thread (w,lane) owns rows 2w, 2w+1 at its 4 j's
#pragma unroll
  for (int rr = 0; rr < 2; ++rr) {
    int r = 2 * w + rr;
    float d0 = red[0][lane][4 * r + 0] + red[1][lane][4 * r + 0] + red[2][lane][4 * r + 0] + red[3][lane][4 * r + 0];
    float d1 = red[0][lane][4 * r + 1] + red[1][lane][4 * r + 1] + red[2][lane][4 * r + 1] + red[3][lane][4 * r + 1];
    float d2 = red[0][lane][4 * r + 2] + red[1][lane][4 * r + 2] + red[2][lane][4 * r + 2] + red[3][lane][4 * r + 2];
    float d3 = red[0][lane][4 * r + 3] + red[1][lane][4 * r + 3] + red[2][lane][4 * r + 3] + red[3][lane][4 * r + 3];
    float ss = waveReduceXor(d0 * d0 + d1 * d1 + d2 * d2 + d3 * d3);
    float inv = 1.0f / (sqrtf(ss) + 1e-6f);
    float4 v = make_float4(d0 * inv, d1 * inv, d2 * inv, d3 * inv);
    *(float4*)&g[(size_t)(n0 + r) * FF + j0] = v;
    if (lane == 0) sqn[n0 + r] = ss * inv * inv;
    ((float4*)&trans[r][0])[lane] = v;
  }
  __syncthreads();
  // coalesced-ish gT write: thread tj owns column j=tj, rows n0..n0+7
  int tj = threadIdx.x;
  float4 lo = make_float4(trans[0][tj], trans[1][tj], trans[2][tj], trans[3][tj]);
  float4 hi = make_float4(trans[4][tj], trans[5][tj], trans[6][tj], trans[7][tj]);
  *(float4*)(gT + (size_t)tj * NN + n0) = lo;
  *(float4*)(gT + (size_t)tj * NN + n0 + 4) = hi;
}

// Pairwise masked loss. Block: (chunk c, i-group of 8). Wave = 64-j tile,
// lane quads split k (4 x 64), shfl_xor reduce; lane quad 0 does epilogue.
// launch_bounds(256,4): cap 128 VGPR — kills the 64-VGPR spill seen in r10.
__global__ void __launch_bounds__(256, 4)
k_pair(const float* __restrict__ g, const float* __restrict__ gT,
       const float* __restrict__ sqn, const int* __restrict__ labels,
       const float* __restrict__ beta, double* __restrict__ acc, int pass) {
  int c = blockIdx.x >> 5, ig = blockIdx.x & 31;
  int i0 = c * 256 + ig * 8;
  int wv = threadIdx.x >> 6;          // j-tile
  int lane = threadIdx.x & 63;
  int ksub = lane >> 4;               // 0..3 -> k segment
  int jl0 = wv * 64 + (lane & 15) * 4;  // chunk-local j base
  float fl1 = 0.f, fl4 = 0.f, fcnt = 0.f;
  if (wv * 64 + 63 >= ig * 8) {       // triangle tile skip (wave-uniform)
    float a[8][4];
#pragma unroll
    for (int r = 0; r < 8; ++r)
#pragma unroll
      for (int jj = 0; jj < 4; ++jj) a[r][jj] = 0.f;
    int kb = ksub * 64;
    const float* gtb = gT + (size_t)c * 256 + jl0;
#pragma unroll 8
    for (int kk = 0; kk < 64; kk += 4) {
      int k = kb + kk;
      float4 b0 = *(const float4*)(gtb + (size_t)(k + 0) * NN);
      float4 b1 = *(const float4*)(gtb + (size_t)(k + 1) * NN);
      float4 b2 = *(const float4*)(gtb + (size_t)(k + 2) * NN);
      float4 b3 = *(const float4*)(gtb + (size_t)(k + 3) * NN);
#pragma unroll
      for (int r = 0; r < 8; ++r) {
        float4 gi = *(const float4*)(g + (size_t)(i0 + r) * FF + k);
        a[r][0] += gi.x * b0.x + gi.y * b1.x + gi.z * b2.x + gi.w * b3.x;
        a[r][1] += gi.x * b0.y + gi.y * b1.y + gi.z * b2.y + gi.w * b3.y;
        a[r][2] += gi.x * b0.z + gi.y * b1.z + gi.z * b2.z + gi.w * b3.z;
        a[r][3] += gi.x * b0.w + gi.y * b1.w + gi.z * b2.w + gi.w * b3.w;
      }
    }
    // reduce over the 4 k-segments: lanes l, l^16, l^32
#pragma unroll
    for (int r = 0; r < 8; ++r)
#pragma unroll
      for (int jj = 0; jj < 4; ++jj) {
        float v = a[r][jj];
        v += __shfl_xor(v, 16, 64);
        v += __shfl_xor(v, 32, 64);
        a[r][jj] = v;
      }
    if (ksub == 0) {
#pragma unroll
      for (int r = 0; r < 8; ++r) {
        int i = i0 + r, il = ig * 8 + r;
        int li = labels[i];
        float sqi = sqn[i];
        bool sti = beta[i] < 0.15f;
#pragma unroll
        for (int jj = 0; jj < 4; ++jj) {
          int jl = jl0 + jj;
          if (jl >= il) {
            int jg = c * 256 + jl;
            int lj = labels[jg];
            if (li != -1 && lj != -1) {
              fcnt += 1.0f;
              if (sti || beta[jg] < 0.15f) {
                float d2 = sqi + sqn[jg] - 2.0f * a[r][jj];
                float d = sqrtf(fmaxf(d2, 1e-12f));
                if (li == lj) {
                  if (jl != il) fl1 += d;
                } else {
                  fl4 += fmaxf(0.f, 1.0f - d);
                }
              }
            }
          }
        }
      }
    }
  }
  fl1 = waveReduce(fl1);
  fl4 = waveReduce(fl4);
  fcnt = waveReduce(fcnt);
  if (lane == 0) {
    if (pass == 0) {
      if (fl1 != 0.f) atomicAdd(&acc[5], (double)fl1);
      if (fl4 != 0.f) atomicAdd(&acc[7], (double)fl4);
      if (fcnt != 0.f) atomicAdd(&acc[8], (double)fcnt);
    } else {
      if (fl1 != 0.f) atomicAdd(&acc[6], (double)fl1);
    }
  }
}

__global__ void k_final(const double* __restrict__ acc, float* __restrict__ out) {
  if (threadIdx.x == 0) {
    double msum = acc[3] + 1e-20;
    out[0] = (float)(acc[0] / msum);
    out[1] = (float)(acc[1] / msum);
    out[2] = (float)(3.0 + acc[2] / msum);
    out[3] = (float)(0.01 * acc[4] / (double)(NN * SS));
    out[4] = (float)((acc[5] + acc[6] + acc[7]) / acc[8]);
  }
}

extern "C" void kernel_launch(void* const* d_in, const int* in_sizes, int n_in,
                              void* d_out, int out_size, void* d_ws, size_t ws_size,
                              hipStream_t stream) {
  const float* rgbs      = (const float*)d_in[0];
  const float* ray_mask  = (const float*)d_in[1];
  const float* rgb_coarse= (const float*)d_in[2];
  const float* rgb_fine  = (const float*)d_in[3];
  const float* beta      = (const float*)d_in[4];
  const float* sig       = (const float*)d_in[5];
  const float* pt        = (const float*)d_in[6];
  const float* wfs       = (const float*)d_in[7];
  const float* scales    = (const float*)d_in[8];
  const float* W1        = (const float*)d_in[9];
  const float* W2        = (const float*)d_in[10];
  const int*   labels    = (const int*)d_in[11];
  float* out = (float*)d_out;

  char* w = (char*)d_ws;
  double* acc = (double*)w;            // 16 doubles
  float* feat = (float*)(w + 256);     // N*64
  float* h    = feat + NN * DD;        // N*256
  float* g    = h + NN * HH;           // N*256
  float* gT   = g + NN * FF;           // N*256
  float* sqn  = gT + NN * FF;          // N

  k_zero<<<1, 64, 0, stream>>>(acc);
  k_scalar<<<16, 256, 0, stream>>>(rgbs, ray_mask, rgb_coarse, rgb_fine, beta, sig, acc);
  k_feat<<<1024, 256, 0, stream>>>(pt, wfs, feat);

  // pass 0: original scales -> loss1, loss4, block count
  k_h<<<256, 256, 0, stream>>>(feat, scales, W1, h, 0);
  k_g<<<512, 256, 0, stream>>>(h, W2, g, gT, sqn);
  k_pair<<<512, 256, 0, stream>>>(g, gT, sqn, labels, beta, acc, 0);

  // pass 1: larger scales -> loss2
  k_h<<<256, 256, 0, stream>>>(feat, scales, W1, h, 1);
  k_g<<<512, 256, 0, stream>>>(h, W2, g, gT, sqn);
  k_pair<<<512, 256, 0, stream>>>(g, gT, sqn, labels, beta, acc, 1);

  k_final<<<1, 64, 0, stream>>>(acc, out);
}

// Round 12
// 299.382 us; speedup vs baseline: 1.3130x; 1.2164x over previous
//
#include <hip/hip_runtime.h>
#include <math.h>

#define NN 4096
#define SS 64
#define DD 64
#define HH 256
#define FF 256
// chunk_size fixed at 256 by setup_inputs(); 16 chunks of 256.
// HARD RULE learned r10/r11: keep per-thread live set under 64 VGPRs —
// the allocator targets 8 waves/EU and spills anything above 64.

__device__ __forceinline__ float waveReduce(float v) {
#pragma unroll
  for (int o = 32; o > 0; o >>= 1) v += __shfl_down(v, o, 64);
  return v;
}
__device__ __forceinline__ float waveReduceXor(float v) {
#pragma unroll
  for (int o = 32; o > 0; o >>= 1) v += __shfl_xor(v, o, 64);
  return v;
}

// acc: 0=c_num 1=f_num 2=b_num 3=msum 4=sig_sum 5=loss1 6=loss2 7=loss4 8=block_count
__global__ void k_zero(double* __restrict__ acc) {
  if (threadIdx.x < 16) acc[threadIdx.x] = 0.0;
}

__global__ void k_scalar(const float* __restrict__ rgbs, const float* __restrict__ ray_mask,
                         const float* __restrict__ coarse, const float* __restrict__ fine,
                         const float* __restrict__ beta, const float* __restrict__ sig,
                         double* __restrict__ acc) {
  int tid = blockIdx.x * blockDim.x + threadIdx.x;  // 4096 threads
  float c = 0.f, f = 0.f, b = 0.f, m = 0.f, s = 0.f;
  if (tid < NN) {
    float mk = ray_mask[tid];
    float bt = beta[tid];
    float inv2b2 = 1.0f / (2.0f * bt * bt);
#pragma unroll
    for (int ch = 0; ch < 3; ++ch) {
      float r = rgbs[tid * 3 + ch];
      float dc = coarse[tid * 3 + ch] - r;
      float df = fine[tid * 3 + ch] - r;
      c += dc * dc * mk;
      f += df * df * inv2b2 * mk;
    }
    c *= 0.5f;
    b = logf(bt) * mk;
    m = mk;
  }
  for (int i = tid; i < NN * SS; i += NN) s += sig[i];
  c = waveReduce(c); f = waveReduce(f); b = waveReduce(b); m = waveReduce(m); s = waveReduce(s);
  if ((threadIdx.x & 63) == 0) {
    atomicAdd(&acc[0], (double)c);
    atomicAdd(&acc[1], (double)f);
    atomicAdd(&acc[2], (double)b);
    atomicAdd(&acc[3], (double)m);
    atomicAdd(&acc[4], (double)s);
  }
}

// feat[n][d] = sum_s pt[n][s][d] * w[n][s].  One wave per n, float4 loads.
__global__ void k_feat(const float* __restrict__ pt, const float* __restrict__ w,
                       float* __restrict__ feat) {
  int wave = (blockIdx.x * blockDim.x + threadIdx.x) >> 6;
  int lane = threadIdx.x & 63;
  if (wave >= NN) return;
  const float4* p4 = (const float4*)(pt + (size_t)wave * SS * DD);
  const float* wr = w + wave * SS;
  float a0 = 0.f, a1 = 0.f, a2 = 0.f, a3 = 0.f;
#pragma unroll
  for (int it = 0; it < 16; ++it) {
    float4 v = p4[it * 64 + lane];
    float ws = wr[it * 4 + (lane >> 4)];
    a0 += v.x * ws; a1 += v.y * ws; a2 += v.z * ws; a3 += v.w * ws;
  }
  a0 += __shfl_xor(a0, 16, 64); a1 += __shfl_xor(a1, 16, 64);
  a2 += __shfl_xor(a2, 16, 64); a3 += __shfl_xor(a3, 16, 64);
  a0 += __shfl_xor(a0, 32, 64); a1 += __shfl_xor(a1, 32, 64);
  a2 += __shfl_xor(a2, 32, 64); a3 += __shfl_xor(a3, 32, 64);
  if (lane < 16) {
    float4 o = make_float4(a0, a1, a2, a3);
    ((float4*)(feat + wave * DD))[lane] = o;
  }
}

// h[n][j] = relu(feat[n][:] @ W1[0:64][j] + scale_n*W1[64][j])
// block: 16 n-rows; wave w -> 4 rows; lane -> 4 j. ~45 VGPR, no spill.
__global__ void k_h(const float* __restrict__ feat, const float* __restrict__ scales,
                    const float* __restrict__ W1, float* __restrict__ h, int larger) {
  int w = threadIdx.x >> 6, lane = threadIdx.x & 63;
  int j0 = 4 * lane;
  int nb = blockIdx.x * 16 + w * 4;
  float a[4][4];
#pragma unroll
  for (int r = 0; r < 4; ++r)
#pragma unroll
    for (int jj = 0; jj < 4; ++jj) a[r][jj] = 0.f;
#pragma unroll 8
  for (int k = 0; k < DD; ++k) {
    float4 wv = *(const float4*)&W1[k * HH + j0];
#pragma unroll
    for (int r = 0; r < 4; ++r) {
      float fv = feat[(nb + r) * DD + k];  // wave-uniform -> s_load
      a[r][0] += fv * wv.x; a[r][1] += fv * wv.y;
      a[r][2] += fv * wv.z; a[r][3] += fv * wv.w;
    }
  }
  float4 wl = *(const float4*)&W1[DD * HH + j0];
#pragma unroll
  for (int r = 0; r < 4; ++r) {
    float sc = scales[nb + r];
    if (larger) sc = sc + fmaxf(0.f, 2.0f - sc) * 0.5f;
    float4 o;
    o.x = fmaxf(a[r][0] + sc * wl.x, 0.f);
    o.y = fmaxf(a[r][1] + sc * wl.y, 0.f);
    o.z = fmaxf(a[r][2] + sc * wl.z, 0.f);
    o.w = fmaxf(a[r][3] + sc * wl.w, 0.f);
    *(float4*)&h[(nb + r) * HH + j0] = o;
  }
}

// g = normalize(h @ W2). Block: 4 n-rows (fits 64 VGPR); waves split k (4x64);
// lane -> 4 j. Cross-wave reduce via padded LDS; wave w owns row w's epilogue.
__global__ void k_g(const float* __restrict__ h, const float* __restrict__ W2,
                    float* __restrict__ g, float* __restrict__ gT, float* __restrict__ sqn) {
  int n0 = blockIdx.x * 4;
  int w = threadIdx.x >> 6, lane = threadIdx.x & 63;
  int j0 = 4 * lane;
  int kb = w * 64;
  float a[4][4];
#pragma unroll
  for (int r = 0; r < 4; ++r)
#pragma unroll
    for (int jj = 0; jj < 4; ++jj) a[r][jj] = 0.f;
#pragma unroll 8
  for (int kk = 0; kk < 64; kk += 4) {
    int k = kb + kk;
    float4 w0 = *(const float4*)&W2[(k + 0) * FF + j0];
    float4 w1 = *(const float4*)&W2[(k + 1) * FF + j0];
    float4 w2 = *(const float4*)&W2[(k + 2) * FF + j0];
    float4 w3 = *(const float4*)&W2[(k + 3) * FF + j0];
#pragma unroll
    for (int r = 0; r < 4; ++r) {
      float4 hv = *(const float4*)&h[(n0 + r) * HH + k];  // wave-uniform
      a[r][0] += hv.x * w0.x + hv.y * w1.x + hv.z * w2.x + hv.w * w3.x;
      a[r][1] += hv.x * w0.y + hv.y * w1.y + hv.z * w2.y + hv.w * w3.y;
      a[r][2] += hv.x * w0.z + hv.y * w1.z + hv.z * w2.z + hv.w * w3.z;
      a[r][3] += hv.x * w0.w + hv.y * w1.w + hv.z * w2.w + hv.w * w3.w;
    }
  }
  __shared__ float red[4][64][17];
  __shared__ float trans[4][FF];
#pragma unroll
  for (int r = 0; r < 4; ++r)
#pragma unroll
    for (int jj = 0; jj < 4; ++jj) red[w][lane][4 * r + jj] = a[r][jj];
  __syncthreads();
  // wave w owns row w: sum the 4 k-partials at each j, normalize.
  {
    int r = w;
    float d0 = red[0][lane][4 * r + 0] + red[1][lane][4 * r + 0] + red[2][lane][4 * r + 0] + red[3][lane][4 * r + 0];
    float d1 = red[0][lane][4 * r + 1] + red[1][lane][4 * r + 1] + red[2][lane][4 * r + 1] + red[3][lane][4 * r + 1];
    float d2 = red[0][lane][4 * r + 2] + red[1][lane][4 * r + 2] + red[2][lane][4 * r + 2] + red[3][lane][4 * r + 2];
    float d3 = red[0][lane][4 * r + 3] + red[1][lane][4 * r + 3] + red[2][lane][4 * r + 3] + red[3][lane][4 * r + 3];
    float ss = waveReduceXor(d0 * d0 + d1 * d1 + d2 * d2 + d3 * d3);
    float inv = 1.0f / (sqrtf(ss) + 1e-6f);
    float4 v = make_float4(d0 * inv, d1 * inv, d2 * inv, d3 * inv);
    *(float4*)&g[(size_t)(n0 + r) * FF + j0] = v;
    if (lane == 0) sqn[n0 + r] = ss * inv * inv;
    ((float4*)&trans[r][0])[lane] = v;
  }
  __syncthreads();
  // gT write: thread tj owns column j=tj, rows n0..n0+3 (one float4).
  int tj = threadIdx.x;
  float4 o = make_float4(trans[0][tj], trans[1][tj], trans[2][tj], trans[3][tj]);
  *(float4*)(gT + (size_t)tj * NN + n0) = o;
}

// Pairwise masked loss. Block: (chunk c, i-group of 4) -> 1024 blocks (fits 64 VGPR).
// Wave = 64-j tile, lane quads split k (4 x 64), shfl_xor reduce; quad 0 epilogue.
__global__ void k_pair(const float* __restrict__ g, const float* __restrict__ gT,
                       const float* __restrict__ sqn, const int* __restrict__ labels,
                       const float* __restrict__ beta, double* __restrict__ acc, int pass) {
  int c = blockIdx.x >> 6, ig = blockIdx.x & 63;
  int i0 = c * 256 + ig * 4;
  int wv = threadIdx.x >> 6;          // j-tile
  int lane = threadIdx.x & 63;
  int ksub = lane >> 4;               // 0..3 -> k segment
  int jl0 = wv * 64 + (lane & 15) * 4;  // chunk-local j base
  float fl1 = 0.f, fl4 = 0.f, fcnt = 0.f;
  if (wv * 64 + 63 >= ig * 4) {       // triangle tile skip (wave-uniform)
    float a[4][4];
#pragma unroll
    for (int r = 0; r < 4; ++r)
#pragma unroll
      for (int jj = 0; jj < 4; ++jj) a[r][jj] = 0.f;
    int kb = ksub * 64;
    const float* gtb = gT + (size_t)c * 256 + jl0;
#pragma unroll 8
    for (int kk = 0; kk < 64; kk += 4) {
      int k = kb + kk;
      float4 b0 = *(const float4*)(gtb + (size_t)(k + 0) * NN);
      float4 b1 = *(const float4*)(gtb + (size_t)(k + 1) * NN);
      float4 b2 = *(const float4*)(gtb + (size_t)(k + 2) * NN);
      float4 b3 = *(const float4*)(gtb + (size_t)(k + 3) * NN);
#pragma unroll
      for (int r = 0; r < 4; ++r) {
        float4 gi = *(const float4*)(g + (size_t)(i0 + r) * FF + k);
        a[r][0] += gi.x * b0.x + gi.y * b1.x + gi.z * b2.x + gi.w * b3.x;
        a[r][1] += gi.x * b0.y + gi.y * b1.y + gi.z * b2.y + gi.w * b3.y;
        a[r][2] += gi.x * b0.z + gi.y * b1.z + gi.z * b2.z + gi.w * b3.z;
        a[r][3] += gi.x * b0.w + gi.y * b1.w + gi.z * b2.w + gi.w * b3.w;
      }
    }
    // reduce over the 4 k-segments: lanes l, l^16, l^32
#pragma unroll
    for (int r = 0; r < 4; ++r)
#pragma unroll
      for (int jj = 0; jj < 4; ++jj) {
        float v = a[r][jj];
        v += __shfl_xor(v, 16, 64);
        v += __shfl_xor(v, 32, 64);
        a[r][jj] = v;
      }
    if (ksub == 0) {
#pragma unroll
      for (int r = 0; r < 4; ++r) {
        int i = i0 + r, il = ig * 4 + r;
        int li = labels[i];
        float sqi = sqn[i];
        bool sti = beta[i] < 0.15f;
#pragma unroll
        for (int jj = 0; jj < 4; ++jj) {
          int jl = jl0 + jj;
          if (jl >= il) {
            int jg = c * 256 + jl;
            int lj = labels[jg];
            if (li != -1 && lj != -1) {
              fcnt += 1.0f;
              if (sti || beta[jg] < 0.15f) {
                float d2 = sqi + sqn[jg] - 2.0f * a[r][jj];
                float d = sqrtf(fmaxf(d2, 1e-12f));
                if (li == lj) {
                  if (jl != il) fl1 += d;
                } else {
                  fl4 += fmaxf(0.f, 1.0f - d);
                }
              }
            }
          }
        }
      }
    }
  }
  fl1 = waveReduce(fl1);
  fl4 = waveReduce(fl4);
  fcnt = waveReduce(fcnt);
  if (lane == 0) {
    if (pass == 0) {
      if (fl1 != 0.f) atomicAdd(&acc[5], (double)fl1);
      if (fl4 != 0.f) atomicAdd(&acc[7], (double)fl4);
      if (fcnt != 0.f) atomicAdd(&acc[8], (double)fcnt);
    } else {
      if (fl1 != 0.f) atomicAdd(&acc[6], (double)fl1);
    }
  }
}

__global__ void k_final(const double* __restrict__ acc, float* __restrict__ out) {
  if (threadIdx.x == 0) {
    double msum = acc[3] + 1e-20;
    out[0] = (float)(acc[0] / msum);
    out[1] = (float)(acc[1] / msum);
    out[2] = (float)(3.0 + acc[2] / msum);
    out[3] = (float)(0.01 * acc[4] / (double)(NN * SS));
    out[4] = (float)((acc[5] + acc[6] + acc[7]) / acc[8]);
  }
}

extern "C" void kernel_launch(void* const* d_in, const int* in_sizes, int n_in,
                              void* d_out, int out_size, void* d_ws, size_t ws_size,
                              hipStream_t stream) {
  const float* rgbs      = (const float*)d_in[0];
  const float* ray_mask  = (const float*)d_in[1];
  const float* rgb_coarse= (const float*)d_in[2];
  const float* rgb_fine  = (const float*)d_in[3];
  const float* beta      = (const float*)d_in[4];
  const float* sig       = (const float*)d_in[5];
  const float* pt        = (const float*)d_in[6];
  const float* wfs       = (const float*)d_in[7];
  const float* scales    = (const float*)d_in[8];
  const float* W1        = (const float*)d_in[9];
  const float* W2        = (const float*)d_in[10];
  const int*   labels    = (const int*)d_in[11];
  float* out = (float*)d_out;

  char* w = (char*)d_ws;
  double* acc = (double*)w;            // 16 doubles
  float* feat = (float*)(w + 256);     // N*64
  float* h    = feat + NN * DD;        // N*256
  float* g    = h + NN * HH;           // N*256
  float* gT   = g + NN * FF;           // N*256
  float* sqn  = gT + NN * FF;          // N

  k_zero<<<1, 64, 0, stream>>>(acc);
  k_scalar<<<16, 256, 0, stream>>>(rgbs, ray_mask, rgb_coarse, rgb_fine, beta, sig, acc);
  k_feat<<<1024, 256, 0, stream>>>(pt, wfs, feat);

  // pass 0: original scales -> loss1, loss4, block count
  k_h<<<256, 256, 0, stream>>>(feat, scales, W1, h, 0);
  k_g<<<1024, 256, 0, stream>>>(h, W2, g, gT, sqn);
  k_pair<<<1024, 256, 0, stream>>>(g, gT, sqn, labels, beta, acc, 0);

  // pass 1: larger scales -> loss2
  k_h<<<256, 256, 0, stream>>>(feat, scales, W1, h, 1);
  k_g<<<1024, 256, 0, stream>>>(h, W2, g, gT, sqn);
  k_pair<<<1024, 256, 0, stream>>>(g, gT, sqn, labels, beta, acc, 1);

  k_final<<<1, 64, 0, stream>>>(acc, out);
}